// Round 14
// baseline (258.135 us; speedup 1.0000x reference)
//
#include <hip/hip_runtime.h>
#include <cmath>

typedef __attribute__((ext_vector_type(8))) short  short8;
typedef __attribute__((ext_vector_type(4))) float  floatx4;
typedef __attribute__((ext_vector_type(8))) unsigned short ushort8;
typedef __attribute__((ext_vector_type(8))) unsigned char uchar8v;

// Accumulator slots spread 64B apart to avoid same-cacheline atomic serialization.
#define SLOT(i) ((i) * 16)
#define ACC_L1   0
#define ACC_MSE  1
#define ACC_ST0  2
#define ACC_ST1  3
#define ACC_SP0  4
#define ACC_SP1  5
#define ACC_HV   6
#define ACC_WV   7
#define ACC_EXP  8
#define ACC_SPAT 9
#define ACC_PERC 10
#define CNT_OFF  240          // perc completion counter (memset'd to 0)
#define SSIM_SLOT(scale, cs, img) (256 + ((scale) * 12 + (cs) * 6 + (img)) * 16)
// zero page for OOB global_load_lds lanes: bytes [12800, 16384) of the
// memset'd acc region — never written by any atomic. Always zero.
#define ZPAGE_FLOAT_OFF 3200

struct GW { float g[11]; };

__device__ __forceinline__ float waveSum(float v) {
#pragma unroll
  for (int o = 32; o > 0; o >>= 1) v += __shfl_down(v, o, 64);
  return v;
}

__device__ __forceinline__ float blockSum256(float v) {
  __shared__ float red[4];
  const int tid = threadIdx.x;
  v = waveSum(v);
  __syncthreads();
  if ((tid & 63) == 0) red[tid >> 6] = v;
  __syncthreads();
  return red[0] + red[1] + red[2] + red[3];
}

// pack 4 floats -> 4 OCP e4m3 bytes (HW cvt, RNE)
__device__ __forceinline__ unsigned int pk_fp8x4(float v0, float v1, float v2, float v3) {
  int p = __builtin_amdgcn_cvt_pk_fp8_f32(v0, v1, 0, false);
  p = __builtin_amdgcn_cvt_pk_fp8_f32(v2, v3, p, true);
  return (unsigned int)p;
}

// async global->LDS, 16B per lane; LDS dest is wave-linear (base + lane*16).
__device__ __forceinline__ void gload16(const unsigned char* g, unsigned char* l) {
  __builtin_amdgcn_global_load_lds(
      (const __attribute__((address_space(1))) void*)g,
      (__attribute__((address_space(3))) void*)l, 16, 0, 0);
}

// shared ssim tile body: computes one (scale, tile, img) contribution.
// sX/sY/sV are caller-provided LDS aliases. bid in [0,259).
__device__ __forceinline__ void ssim_tile(
    int bid, int img, const float* __restrict__ yt, const float* __restrict__ yp,
    const float* __restrict__ pyrX, const float* __restrict__ pyrY,
    float* __restrict__ acc, const GW& gw,
    float (*sX)[27], float (*sY)[27], float (*sV)[16][27]) {
  int s = 0;
  if (bid >= 196) s = 1;
  if (bid >= 245) s = 2;
  if (bid >= 254) s = 3;
  if (bid >= 258) s = 4;
  const int cumA[5]   = {0, 196, 245, 254, 258};
  const int tilesA[5] = {14, 7, 3, 2, 1};
  const int dimsA[5]  = {224, 112, 56, 28, 14};
  const int offsA[5]  = {0, 0, 75264, 94080, 98784};
  const int t = bid - cumA[s];
  const int tiles = tilesA[s];
  const int n = dimsA[s];
  const int m = n - 10;
  const int tid = threadIdx.x;
  const int ty0 = (t / tiles) * 16;
  const int tx0 = (t - (t / tiles) * tiles) * 16;
  const float* Xb = ((s == 0) ? yt : pyrX + offsA[s]) + (size_t)img * n * n;
  const float* Yb = ((s == 0) ? yp : pyrY + offsA[s]) + (size_t)img * n * n;

  for (int e = tid; e < 26 * 26; e += 256) {
    const int r = e / 26, c = e - (e / 26) * 26;
    const int gy = ty0 + r, gx = tx0 + c;
    float xv = 0.f, yv = 0.f;
    if (gy < n && gx < n) {
      xv = Xb[(size_t)gy * n + gx];
      yv = Yb[(size_t)gy * n + gx];
    }
    sX[r][c] = xv; sY[r][c] = yv;
  }
  __syncthreads();

  for (int e = tid; e < 16 * 26; e += 256) {
    const int r = e / 26, c = e - (e / 26) * 26;
    float sx = 0.f, sy = 0.f, sxx = 0.f, syy = 0.f, sxy = 0.f;
#pragma unroll
    for (int tt = 0; tt < 11; ++tt) {
      const float xv = sX[r + tt][c];
      const float yv = sY[r + tt][c];
      const float g = gw.g[tt];
      sx += g * xv; sy += g * yv;
      sxx += g * xv * xv; syy += g * yv * yv; sxy += g * xv * yv;
    }
    sV[0][r][c] = sx; sV[1][r][c] = sy;
    sV[2][r][c] = sxx; sV[3][r][c] = syy; sV[4][r][c] = sxy;
  }
  __syncthreads();

  float sv = 0.f, cv = 0.f;
  {
    const int r = tid >> 4, c = tid & 15;
    if (ty0 + r < m && tx0 + c < m) {
      float mu1 = 0.f, mu2 = 0.f, e11 = 0.f, e22 = 0.f, e12 = 0.f;
#pragma unroll
      for (int tt = 0; tt < 11; ++tt) {
        const float g = gw.g[tt];
        mu1 += g * sV[0][r][c + tt];
        mu2 += g * sV[1][r][c + tt];
        e11 += g * sV[2][r][c + tt];
        e22 += g * sV[3][r][c + tt];
        e12 += g * sV[4][r][c + tt];
      }
      const float C1 = 1e-4f, C2 = 9e-4f;
      const float s11 = e11 - mu1 * mu1;
      const float s22 = e22 - mu2 * mu2;
      const float s12 = e12 - mu1 * mu2;
      cv = (2.f * s12 + C2) / (s11 + s22 + C2);
      sv = ((2.f * mu1 * mu2 + C1) / (mu1 * mu1 + mu2 * mu2 + C1)) * cv;
    }
  }
  float tsum = blockSum256(sv);
  if (tid == 0) atomicAdd(acc + SSIM_SLOT(s, 0, img), tsum);
  tsum = blockSum256(cv);
  if (tid == 0) atomicAdd(acc + SSIM_SLOT(s, 1, img), tsum);
}

// ---------------- mega front-section kernel (R8 structure, unchanged) ------

struct PrepArgs {
  const float* w[6];
  int co[6], ci[6];
  int wcum[7];          // element units
  unsigned char* zp[6];
  int zH[6];
  int zcum[7];          // 16B-chunk units
};

struct MegaArgs {
  PrepArgs pa;
  unsigned char* wdst;
  const float* w0;
  const float* b0;
  unsigned char* c1;
  float* pyrX;
  float* pyrY;
  float* acc;
  int nPrep, nBasic, nPyr, nPS, nW4;
};

__global__ __launch_bounds__(256) void mega_k(MegaArgs A,
                                              const float* __restrict__ yt,
                                              const float* __restrict__ yp) {
  __shared__ float smem[684];
  const int tid = threadIdx.x;
  int bid = blockIdx.x;

  // ---------- prep (vectorized) ----------
  if (bid < A.nPrep) {
    const int idx = bid * 256 + tid;
    const PrepArgs& a = A.pa;
    if (idx < A.nW4) {
      const int e0 = idx * 4;
      int L = 0;
      while (e0 >= a.wcum[L + 1]) ++L;
      const int r = e0 - a.wcum[L];
      const int Cin = a.ci[L];
      const int cin = r % Cin;
      const int t = r / Cin;
      const int tap = t % 9;
      const int cout = t / 9;
      const float* wsrc = a.w[L] + ((size_t)cout * Cin + cin) * 9 + tap;
      *(unsigned int*)(A.wdst + e0) =
          pk_fp8x4(wsrc[0] * 8.f, wsrc[9] * 8.f, wsrc[18] * 8.f, wsrc[27] * 8.f);
      return;
    }
    const int zi = idx - A.nW4;
    if (zi >= a.zcum[6]) return;
    int b = 0;
    while (zi >= a.zcum[b + 1]) ++b;
    const int H = a.zH[b];
    const int rowE = (H + 2) * 32;
    const int perC = (2 * rowE + 2 * H * 32) >> 4;   // 16B chunks per plane
    const int k = zi - a.zcum[b];
    const int pl = k / perC;
    const int k0 = (k - pl * perC) << 4;
    size_t o;
    if (k0 < rowE) o = k0;
    else if (k0 < 2 * rowE) o = (size_t)(H + 1) * rowE + (k0 - rowE);
    else {
      const int kk = k0 - 2 * rowE;
      const int y = kk / 64 + 1;
      const int r = kk & 63;
      o = (size_t)y * rowE + ((r < 32) ? (size_t)r : ((size_t)(H + 1) * 32 + (r - 32)));
    }
    *(uint4*)(a.zp[b] + (size_t)pl * (H + 2) * rowE + o) = (uint4){0, 0, 0, 0};
    return;
  }
  bid -= A.nPrep;

  // ---------- basic_stats ----------
  if (bid < A.nBasic) {
    float* acc = A.acc;
    const int i4 = bid * 256 + tid;  // 0..75263
    const int idx = i4 * 4;
    const float4 t4 = *(const float4*)(yt + idx);
    const float4 p4 = *(const float4*)(yp + idx);
    float l1 = 0.f, mse = 0.f, st0 = 0.f, st1 = 0.f, sp0 = 0.f, sp1 = 0.f, hv = 0.f, wv = 0.f;
#define BTERM(tt, pp) { const float d = (pp) - (tt); const float ad = fabsf(d); \
                        l1 += (ad < 1.f) ? 0.5f * d * d : ad - 0.5f; mse += d * d; }
    BTERM(t4.x, p4.x) BTERM(t4.y, p4.y) BTERM(t4.z, p4.z) BTERM(t4.w, p4.w)
#undef BTERM
    const float ts = t4.x + t4.y + t4.z + t4.w;
    const float ps = p4.x + p4.y + p4.z + p4.w;
    if (i4 < 37632) { st0 = ts; sp0 = ps; } else { st1 = ts; sp1 = ps; }
    const int h = (idx / 224) % 224;
    if (h < 223) {
      const float4 pn = *(const float4*)(yp + idx + 224);
      float d;
      d = pn.x - p4.x; hv += d * d;
      d = pn.y - p4.y; hv += d * d;
      d = pn.z - p4.z; hv += d * d;
      d = pn.w - p4.w; hv += d * d;
    }
    {
      const int w = idx % 224;
      float d;
      d = p4.y - p4.x; wv += d * d;
      d = p4.z - p4.y; wv += d * d;
      d = p4.w - p4.z; wv += d * d;
      if (w < 220) { d = yp[idx + 4] - p4.w; wv += d * d; }
    }
    float s;
    s = blockSum256(l1);  if (tid == 0) atomicAdd(acc + SLOT(ACC_L1), s);
    s = blockSum256(mse); if (tid == 0) atomicAdd(acc + SLOT(ACC_MSE), s);
    s = blockSum256(st0); if (tid == 0) atomicAdd(acc + SLOT(ACC_ST0), s);
    s = blockSum256(st1); if (tid == 0) atomicAdd(acc + SLOT(ACC_ST1), s);
    s = blockSum256(sp0); if (tid == 0) atomicAdd(acc + SLOT(ACC_SP0), s);
    s = blockSum256(sp1); if (tid == 0) atomicAdd(acc + SLOT(ACC_SP1), s);
    s = blockSum256(hv);  if (tid == 0) atomicAdd(acc + SLOT(ACC_HV), s);
    s = blockSum256(wv);  if (tid == 0) atomicAdd(acc + SLOT(ACC_WV), s);
    return;
  }
  bid -= A.nBasic;

  // ---------- pyramid ----------
  if (bid < A.nPyr) {
    float (*sA)[17] = (float(*)[17])smem;          // 272
    float (*s1)[9]  = (float(*)[9])(smem + 272);   // 72
    float (*s2)[5]  = (float(*)[5])(smem + 344);   // 20
    float (*s3)[3]  = (float(*)[3])(smem + 364);   // 6
    const int tile = bid % 196;
    const int img = (bid / 196) % 6;
    const int zt = bid / (196 * 6);
    const int ty = tile / 14, tx = tile - ty * 14;
    const float* src = (zt ? yp : yt) + (size_t)img * 224 * 224;
    float* dst = zt ? A.pyrY : A.pyrX;
    const int r = tid >> 4, c = tid & 15;
    sA[r][c] = src[(size_t)(ty * 16 + r) * 224 + tx * 16 + c];
    __syncthreads();
    if (tid < 64) {
      const int r1 = tid >> 3, c1 = tid & 7;
      const float m = 0.25f * (sA[2 * r1][2 * c1] + sA[2 * r1][2 * c1 + 1] +
                               sA[2 * r1 + 1][2 * c1] + sA[2 * r1 + 1][2 * c1 + 1]);
      dst[(size_t)img * 12544 + (ty * 8 + r1) * 112 + tx * 8 + c1] = m;
      s1[r1][c1] = m;
    }
    __syncthreads();
    if (tid < 16) {
      const int r2 = tid >> 2, c2 = tid & 3;
      const float m = 0.25f * (s1[2 * r2][2 * c2] + s1[2 * r2][2 * c2 + 1] +
                               s1[2 * r2 + 1][2 * c2] + s1[2 * r2 + 1][2 * c2 + 1]);
      dst[75264 + (size_t)img * 3136 + (ty * 4 + r2) * 56 + tx * 4 + c2] = m;
      s2[r2][c2] = m;
    }
    __syncthreads();
    if (tid < 4) {
      const int r3 = tid >> 1, c3 = tid & 1;
      const float m = 0.25f * (s2[2 * r3][2 * c3] + s2[2 * r3][2 * c3 + 1] +
                               s2[2 * r3 + 1][2 * c3] + s2[2 * r3 + 1][2 * c3 + 1]);
      dst[94080 + (size_t)img * 784 + (ty * 2 + r3) * 28 + tx * 2 + c3] = m;
      s3[r3][c3] = m;
    }
    __syncthreads();
    if (tid == 0) {
      const float m = 0.25f * (s3[0][0] + s3[0][1] + s3[1][0] + s3[1][1]);
      dst[98784 + (size_t)img * 196 + ty * 14 + tx] = m;
    }
    return;
  }
  bid -= A.nPyr;

  // ---------- pooled-lum tile + spat + exposure ----------
  if (bid < A.nPS) {
    float* acc = A.acc;
    float (*sOp)[19] = (float(*)[19])smem;          // 18x19
    float (*sEp)[19] = (float(*)[19])(smem + 342);  // 18x19
    const int b = bid >> 4;                 // img
    const int tq = bid & 15;
    const int ty0 = (tq >> 2) * 16, tx0 = (tq & 3) * 16;
    for (int e = tid; e < 18 * 18; e += 256) {
      const int r = e / 18, c = e - (e / 18) * 18;
      const int gy = ty0 - 1 + r, gx = tx0 - 1 + c;
      float vo = 0.f, ve = 0.f;
      if (gy >= 0 && gy < 56 && gx >= 0 && gx < 56) {
        float so = 0.f, se = 0.f;
        for (int ch = 0; ch < 3; ++ch)
#pragma unroll
          for (int dy = 0; dy < 4; ++dy) {
            const size_t off = (((size_t)b * 3 + ch) * 224 + (gy * 4 + dy)) * 224 + gx * 4;
            const float4 a = *(const float4*)(yt + off);
            const float4 ee = *(const float4*)(yp + off);
            so += a.x + a.y + a.z + a.w;
            se += ee.x + ee.y + ee.z + ee.w;
          }
        vo = so * (1.f / 48.f);
        ve = se * (1.f / 48.f);
      }
      sOp[r][c] = vo; sEp[r][c] = ve;
    }
    __syncthreads();
    float v = 0.f;
    {
      const int r = tid >> 4, c = tid & 15;
      const int gy = ty0 + r, gx = tx0 + c;
      if (gy < 56 && gx < 56) {
        const float oc = sOp[r + 1][c + 1], ec = sEp[r + 1][c + 1];
        const float ol = sOp[r + 1][c],     el = sEp[r + 1][c];
        const float orr = sOp[r + 1][c + 2], er = sEp[r + 1][c + 2];
        const float ou = sOp[r][c + 1],     eu = sEp[r][c + 1];
        const float od = sOp[r + 2][c + 1], ed = sEp[r + 2][c + 1];
        float d;
        d = (oc - ol) - (ec - el);   v += d * d;
        d = (oc - orr) - (ec - er);  v += d * d;
        d = (oc - ou) - (ec - eu);   v += d * d;
        d = (oc - od) - (ec - ed);   v += d * d;
      }
    }
    const float t = blockSum256(v);
    if (tid == 0) atomicAdd(acc + SLOT(ACC_SPAT), t);
    if (tid < 16) {
      const int ey = tid >> 2, ex = tid & 3;
      if (ty0 + 4 * ey < 56 && tx0 + 4 * ex < 56) {
        float ssum = 0.f;
#pragma unroll
        for (int dy = 0; dy < 4; ++dy)
#pragma unroll
          for (int dx = 0; dx < 4; ++dx)
            ssum += sEp[4 * ey + dy + 1][4 * ex + dx + 1];
        const float m = ssum * (1.f / 16.f) - 0.6f;
        atomicAdd(acc + SLOT(ACC_EXP), m * m);
      }
    }
    return;
  }
  bid -= A.nPS;

  // ---------- conv1 ----------
  {
    float (*sIn)[10][12] = (float(*)[10][12])smem;
    const int zf = bid / 784;
    const int rem = bid - zf * 784;
    const int by = rem / 28, bx = rem - by * 28;
    const int tx = tid & 7, ty = (tid >> 3) & 7, tz = tid >> 6;
    const int img = zf >> 1;
    const int zb = zf & 1;
    const float* in = ((img >> 1) ? yp : yt) + (size_t)(img & 1) * 3 * 224 * 224;
    const int x0 = bx << 3, y0 = by << 3;
    const int x = x0 + tx, y = y0 + ty;
    int wrow = (zb * 32 + tz * 8) * 27;
    wrow = __builtin_amdgcn_readfirstlane(wrow);

    for (int el = tid; el < 300; el += 256) {
      const int ci = el / 100;
      const int r2 = el - ci * 100;
      const int r = r2 / 10, cl = r2 - r * 10;
      const int gy = y0 - 1 + r, gx = x0 - 1 + cl;
      float v = 0.f;
      if (gy >= 0 && gy < 224 && gx >= 0 && gx < 224)
        v = in[((size_t)ci * 224 + gy) * 224 + gx];
      sIn[ci][r][cl] = v;
    }
    __syncthreads();

    float a[8];
#pragma unroll
    for (int j = 0; j < 8; ++j) a[j] = 0.f;
#pragma unroll
    for (int ci = 0; ci < 3; ++ci) {
      float xv[9];
#pragma unroll
      for (int ky = 0; ky < 3; ++ky)
#pragma unroll
        for (int kx = 0; kx < 3; ++kx)
          xv[ky * 3 + kx] = sIn[ci][ty + ky][tx + kx];
      const float* wp = A.w0 + wrow + ci * 9;
#pragma unroll
      for (int j = 0; j < 8; ++j)
#pragma unroll
        for (int k = 0; k < 9; ++k)
          a[j] = fmaf(xv[k], wp[27 * j + k], a[j]);
    }
    const int coB = zb * 32 + tz * 8;
    float r[8];
#pragma unroll
    for (int j = 0; j < 8; ++j) r[j] = fmaxf(a[j] + A.b0[coB + j], 0.f);
    const size_t o = (((size_t)(zb * 4 + img) * 226 + (y + 1)) * 226 + (x + 1)) * 32 + tz * 8;
    uint2 rv;
    rv.x = pk_fp8x4(r[0], r[1], r[2], r[3]);
    rv.y = pk_fp8x4(r[4], r[5], r[6], r[7]);
    *(uint2*)(A.c1 + o) = rv;
  }
}

// ---------------- VGG conv (fp8 e4m3, channel-block-major) ----------------
// Activation layout: buf[zb][img][H+2][W+2][32]. Staging = global_load_lds
// width=16 (R9, m151). DB=false: single-buffer 2-barrier, 4 blocks/CU.
// POOL=true (R13): fused 2x2 maxpool epilogue (windows align inside the
// block tile; byte-exact vs the old pool_nhwc; kills the T0 round-trip).
template<int CIN, bool DB, bool POOL>
__global__ __launch_bounds__(256, (DB ? 2 : 4)) void conv_mfma(
    const unsigned char* __restrict__ in, const unsigned char* __restrict__ wtp,
    const float* __restrict__ bias, unsigned char* __restrict__ out,
    const float* __restrict__ zpage, int W, int rowsPI) {
  constexpr int NSLAB = CIN / 32;
  constexpr int NBUF = DB ? 2 : 1;
  constexpr int ASTB = 304;
  constexpr int BSTB = 48;
  constexpr int NBRUN = 6 * 66;
  constexpr int NPX = 66;
  constexpr int ASLOT = 32 * 19;
  constexpr int BSLOT = NBRUN * 3;
  constexpr int NAI = 3;
  constexpr int NBI = 5;
  __shared__ __align__(16) unsigned char As[NBUF][32 * ASTB];
  __shared__ __align__(16) unsigned char Bs[NBUF][NBRUN * BSTB];

  const int tid = threadIdx.x;
  const int lane = tid & 63;
  const int wave = tid >> 6;
  const int quad = lane >> 4;
  const int lr = lane & 15;
  const int img = blockIdx.y / rowsPI;
  const int y0 = (blockIdx.y - img * rowsPI) * 4;
  const int x0 = blockIdx.x * 64;
  const int cob = blockIdx.z * 32;
  const int Wp = W + 2;
  const int H = rowsPI * 4;
  const size_t IPL = (size_t)(H + 2) * Wp * 32;
  const unsigned char* inI = in + (size_t)img * IPL;
  const int Wo = W >> 1, Ho = H >> 1;
  const size_t OPL = POOL ? (size_t)(Ho + 2) * (Wo + 2) * 32 : IPL;
  unsigned char* outI = out + ((size_t)blockIdx.z * 4 + img) * OPL;

  floatx4 acc[2][4];
#pragma unroll
  for (int m = 0; m < 2; ++m)
#pragma unroll
    for (int n = 0; n < 4; ++n) acc[m][n] = (floatx4){0.f, 0.f, 0.f, 0.f};

  const int abase = lr * ASTB + quad * 8;

  const unsigned char* aptr[NAI];
  bool aok[NAI];
#pragma unroll
  for (int i = 0; i < NAI; ++i) {
    const int sl = tid + i * 256;
    aok[i] = sl < ASLOT;
    const int cout = aok[i] ? (sl / 19) : 0;
    const int r = sl - cout * 19;
    const int rr = (r >= 18) ? 17 : r;
    const int tap = rr >> 1, part = rr & 1;
    aptr[i] = wtp + ((size_t)(cob + cout) * 9 + tap) * CIN + part * 16;
  }
  const unsigned char* bptr[NBI];
  unsigned int bstep[NBI];
  bool bok[NBI];
#pragma unroll
  for (int i = 0; i < NBI; ++i) {
    const int sl = tid + i * 256;
    bok[i] = sl < BSLOT;
    const int run = sl / 3;
    const int r = sl - run * 3;
    const int part = (r >= 2) ? 1 : r;
    const int row = run / NPX;
    const int px = run - row * NPX;
    const int gx = x0 + px;
    if (bok[i] && gx < Wp) {
      bptr[i] = inI + ((size_t)(y0 + row) * Wp + gx) * 32 + part * 16;
      bstep[i] = (unsigned int)(4 * IPL);
    } else {
      bptr[i] = (const unsigned char*)zpage;
      bstep[i] = 0;
    }
  }

  auto stage = [&](int buf) {
#pragma unroll
    for (int i = 0; i < NAI; ++i)
      if (aok[i]) {
        gload16(aptr[i], As[buf] + (tid + i * 256) * 16);
        aptr[i] += 32;
      }
#pragma unroll
    for (int i = 0; i < NBI; ++i)
      if (bok[i]) {
        gload16(bptr[i], Bs[buf] + (tid + i * 256) * 16);
        bptr[i] += bstep[i];
      }
  };

  auto mfma_slab = [&](int buf) {
#pragma unroll
    for (int dy = 0; dy < 3; ++dy)
#pragma unroll
      for (int dx = 0; dx < 3; ++dx) {
        const int tap = dy * 3 + dx;
        const long af0 = *(const long*)(As[buf] + abase + tap * 32);
        const long af1 = *(const long*)(As[buf] + abase + 16 * ASTB + tap * 32);
        long bfr[4];
#pragma unroll
        for (int n = 0; n < 4; ++n)
          bfr[n] = *(const long*)(Bs[buf] + ((wave + dy) * NPX + n * 16 + lr + dx) * BSTB + quad * 8);
#pragma unroll
        for (int n = 0; n < 4; ++n) {
          acc[0][n] = __builtin_amdgcn_mfma_f32_16x16x32_fp8_fp8(af0, bfr[n], acc[0][n], 0, 0, 0);
          acc[1][n] = __builtin_amdgcn_mfma_f32_16x16x32_fp8_fp8(af1, bfr[n], acc[1][n], 0, 0, 0);
        }
      }
  };

  if constexpr (!DB) {
    for (int s = 0; s < NSLAB; ++s) {
      __syncthreads();
      stage(0);
      __syncthreads();
      mfma_slab(0);
    }
  } else {
    stage(0);
    __syncthreads();
    for (int s = 0; s < NSLAB; ++s) {
      const int cur = s & 1;
      if (s + 1 < NSLAB) stage(cur ^ 1);
      mfma_slab(cur);
      __syncthreads();
    }
  }

  if constexpr (!POOL) {
#pragma unroll
    for (int m = 0; m < 2; ++m) {
      const int cb = cob + m * 16 + quad * 4;
#pragma unroll
      for (int n = 0; n < 4; ++n) {
        const int px = x0 + n * 16 + lr;
        if (px < W) {
          const float v0 = fmaxf(acc[m][n].x * 0.125f + bias[cb + 0], 0.f);
          const float v1 = fmaxf(acc[m][n].y * 0.125f + bias[cb + 1], 0.f);
          const float v2 = fmaxf(acc[m][n].z * 0.125f + bias[cb + 2], 0.f);
          const float v3 = fmaxf(acc[m][n].w * 0.125f + bias[cb + 3], 0.f);
          *(unsigned int*)(outI + ((size_t)(y0 + wave + 1) * Wp + px + 1) * 32 +
                           m * 16 + quad * 4) = pk_fp8x4(v0, v1, v2, v3);
        }
      }
    }
  } else {
    // fused 2x2 maxpool epilogue via LDS tile sT[4 rows][64 px][32 ch]
    __syncthreads();   // all waves done reading Bs
    unsigned char* sT = Bs[0];
#pragma unroll
    for (int m = 0; m < 2; ++m) {
      const int cb = cob + m * 16 + quad * 4;
#pragma unroll
      for (int n = 0; n < 4; ++n) {
        const int px = n * 16 + lr;
        const float v0 = fmaxf(acc[m][n].x * 0.125f + bias[cb + 0], 0.f);
        const float v1 = fmaxf(acc[m][n].y * 0.125f + bias[cb + 1], 0.f);
        const float v2 = fmaxf(acc[m][n].z * 0.125f + bias[cb + 2], 0.f);
        const float v3 = fmaxf(acc[m][n].w * 0.125f + bias[cb + 3], 0.f);
        *(unsigned int*)(sT + ((wave * 64 + px) * 32 + m * 16 + quad * 4)) =
            pk_fp8x4(v0, v1, v2, v3);
      }
    }
    __syncthreads();
    const int ch8 = (tid & 3) * 8;
    const int co = (tid >> 2) & 31;
    const int ro = tid >> 7;
    const int pxo = (x0 >> 1) + co;
    if (pxo < Wo) {
      const uchar8v a = *(const uchar8v*)(sT + ((2 * ro) * 64 + 2 * co) * 32 + ch8);
      const uchar8v b = *(const uchar8v*)(sT + ((2 * ro) * 64 + 2 * co + 1) * 32 + ch8);
      const uchar8v c = *(const uchar8v*)(sT + ((2 * ro + 1) * 64 + 2 * co) * 32 + ch8);
      const uchar8v d = *(const uchar8v*)(sT + ((2 * ro + 1) * 64 + 2 * co + 1) * 32 + ch8);
      const uchar8v r = __builtin_elementwise_max(__builtin_elementwise_max(a, b),
                                                  __builtin_elementwise_max(c, d));
      *(uchar8v*)(outI + ((size_t)((y0 >> 1) + ro + 1) * (Wo + 2) + (pxo + 1)) * 32 + ch8) = r;
    }
  }
}

// ---------------- deep conv (W=56, DB) + MS-SSIM filler blocks --------------
// R14: deep layers run at 1.75 blocks/CU with >50% of CUs idle; the ssim
// tiles (independent of everything but final) ride here as z>=8 blocks
// instead of gating L3 via conv2's dispatch. LDS aliases into As/Bs (57.5KB
// already allocated — no inflation, R7's failure mode avoided).
template<int CIN>
__global__ __launch_bounds__(256, 2) void conv_deep_ssim_k(
    const unsigned char* __restrict__ in, const unsigned char* __restrict__ wtp,
    const float* __restrict__ bias, unsigned char* __restrict__ out,
    const float* __restrict__ zpage,
    const float* __restrict__ yt, const float* __restrict__ yp,
    const float* __restrict__ pyrX, const float* __restrict__ pyrY,
    float* __restrict__ acc_g, GW gw, int tileBase, int nTiles) {
  constexpr int NSLAB = CIN / 32;
  constexpr int ASTB = 304;
  constexpr int BSTB = 48;
  constexpr int NBRUN = 6 * 66;
  constexpr int NPX = 66;
  constexpr int ASLOT = 32 * 19;
  constexpr int BSLOT = NBRUN * 3;
  constexpr int NAI = 3;
  constexpr int NBI = 5;
  const int W = 56, rowsPI = 14;
  __shared__ __align__(16) unsigned char As[2][32 * ASTB];
  __shared__ __align__(16) unsigned char Bs[2][NBRUN * BSTB];

  const int tid = threadIdx.x;

  if (blockIdx.z >= 8) {
    // ---------- ssim filler tiles (block-uniform branch) ----------
    const int sl = (blockIdx.z - 8) * 56 + blockIdx.y;
    if (sl >= nTiles) return;
    const int tile = tileBase + sl;
    const int img = tile / 259;
    const int bid = tile - img * 259;
    float (*sX)[27] = (float(*)[27])&As[0][0];           // 2808B
    float (*sY)[27] = (float(*)[27])(&As[0][0] + 2816);  // 2808B
    float (*sV)[16][27] = (float(*)[16][27])&Bs[0][0];   // 8640B
    ssim_tile(bid, img, yt, yp, pyrX, pyrY, acc_g, gw, sX, sY, sV);
    return;
  }

  // ---------- conv (R10 DB structure, byte-identical) ----------
  const int lane = tid & 63;
  const int wave = tid >> 6;
  const int quad = lane >> 4;
  const int lr = lane & 15;
  const int img = blockIdx.y / rowsPI;
  const int y0 = (blockIdx.y - img * rowsPI) * 4;
  const int x0 = blockIdx.x * 64;
  const int cob = blockIdx.z * 32;
  const int Wp = W + 2;
  const int H = rowsPI * 4;
  const size_t IPL = (size_t)(H + 2) * Wp * 32;
  const unsigned char* inI = in + (size_t)img * IPL;
  unsigned char* outI = out + ((size_t)blockIdx.z * 4 + img) * IPL;

  floatx4 acc[2][4];
#pragma unroll
  for (int m = 0; m < 2; ++m)
#pragma unroll
    for (int n = 0; n < 4; ++n) acc[m][n] = (floatx4){0.f, 0.f, 0.f, 0.f};

  const int abase = lr * ASTB + quad * 8;

  const unsigned char* aptr[NAI];
  bool aok[NAI];
#pragma unroll
  for (int i = 0; i < NAI; ++i) {
    const int sl = tid + i * 256;
    aok[i] = sl < ASLOT;
    const int cout = aok[i] ? (sl / 19) : 0;
    const int r = sl - cout * 19;
    const int rr = (r >= 18) ? 17 : r;
    const int tap = rr >> 1, part = rr & 1;
    aptr[i] = wtp + ((size_t)(cob + cout) * 9 + tap) * CIN + part * 16;
  }
  const unsigned char* bptr[NBI];
  unsigned int bstep[NBI];
  bool bok[NBI];
#pragma unroll
  for (int i = 0; i < NBI; ++i) {
    const int sl = tid + i * 256;
    bok[i] = sl < BSLOT;
    const int run = sl / 3;
    const int r = sl - run * 3;
    const int part = (r >= 2) ? 1 : r;
    const int row = run / NPX;
    const int px = run - row * NPX;
    const int gx = x0 + px;
    if (bok[i] && gx < Wp) {
      bptr[i] = inI + ((size_t)(y0 + row) * Wp + gx) * 32 + part * 16;
      bstep[i] = (unsigned int)(4 * IPL);
    } else {
      bptr[i] = (const unsigned char*)zpage;
      bstep[i] = 0;
    }
  }

  auto stage = [&](int buf) {
#pragma unroll
    for (int i = 0; i < NAI; ++i)
      if (aok[i]) {
        gload16(aptr[i], As[buf] + (tid + i * 256) * 16);
        aptr[i] += 32;
      }
#pragma unroll
    for (int i = 0; i < NBI; ++i)
      if (bok[i]) {
        gload16(bptr[i], Bs[buf] + (tid + i * 256) * 16);
        bptr[i] += bstep[i];
      }
  };

  auto mfma_slab = [&](int buf) {
#pragma unroll
    for (int dy = 0; dy < 3; ++dy)
#pragma unroll
      for (int dx = 0; dx < 3; ++dx) {
        const int tap = dy * 3 + dx;
        const long af0 = *(const long*)(As[buf] + abase + tap * 32);
        const long af1 = *(const long*)(As[buf] + abase + 16 * ASTB + tap * 32);
        long bfr[4];
#pragma unroll
        for (int n = 0; n < 4; ++n)
          bfr[n] = *(const long*)(Bs[buf] + ((wave + dy) * NPX + n * 16 + lr + dx) * BSTB + quad * 8);
#pragma unroll
        for (int n = 0; n < 4; ++n) {
          acc[0][n] = __builtin_amdgcn_mfma_f32_16x16x32_fp8_fp8(af0, bfr[n], acc[0][n], 0, 0, 0);
          acc[1][n] = __builtin_amdgcn_mfma_f32_16x16x32_fp8_fp8(af1, bfr[n], acc[1][n], 0, 0, 0);
        }
      }
  };

  stage(0);
  __syncthreads();
  for (int s = 0; s < NSLAB; ++s) {
    const int cur = s & 1;
    if (s + 1 < NSLAB) stage(cur ^ 1);
    mfma_slab(cur);
    __syncthreads();
  }

#pragma unroll
  for (int m = 0; m < 2; ++m) {
    const int cb = cob + m * 16 + quad * 4;
#pragma unroll
    for (int n = 0; n < 4; ++n) {
      const int px = x0 + n * 16 + lr;
      if (px < W) {
        const float v0 = fmaxf(acc[m][n].x * 0.125f + bias[cb + 0], 0.f);
        const float v1 = fmaxf(acc[m][n].y * 0.125f + bias[cb + 1], 0.f);
        const float v2 = fmaxf(acc[m][n].z * 0.125f + bias[cb + 2], 0.f);
        const float v3 = fmaxf(acc[m][n].w * 0.125f + bias[cb + 3], 0.f);
        *(unsigned int*)(outI + ((size_t)(y0 + wave + 1) * Wp + px + 1) * 32 +
                         m * 16 + quad * 4) = pk_fp8x4(v0, v1, v2, v3);
      }
    }
  }
}

// perceptual + final combine (R14: last-block pattern via atomic counter).
// Stream order guarantees all earlier kernels' atomics are visible when this
// kernel starts; per-block __threadfence before the counter add orders the
// PERC contributions. Counter at acc[CNT_OFF], zeroed by the memset.
#define FP8D(av, bv, J) { const float dd = __builtin_amdgcn_cvt_f32_fp8((av), (J)) - \
                                           __builtin_amdgcn_cvt_f32_fp8((bv), (J)); \
                          v = fmaf(dd, dd, v); }
__global__ __launch_bounds__(256) void perc_final_k(const unsigned char* __restrict__ f,
                                                    float* __restrict__ acc,
                                                    float* __restrict__ out) {
  const int PER = 56 * 56 * 256 / 8;
  const size_t PL = (size_t)58 * 58 * 32;
  float v = 0.f;
  for (int ch = blockIdx.x * 256 + threadIdx.x; ch < 2 * PER; ch += 256 * 256) {
    const int q = ch / PER;
    const int r = ch - q * PER;
    const int e = r * 8;
    const int c = e & 255;
    const int p = e >> 8;
    const int x = p % 56, y = p / 56;
    const int zb = c >> 5;
    const int cw = c & 31;
    const size_t o = (size_t)(zb * 4 + q) * PL + ((size_t)(y + 1) * 58 + (x + 1)) * 32 + cw;
    const uint2 a = *(const uint2*)(f + o);
    const uint2 b = *(const uint2*)(f + o + 2 * PL);
    FP8D(a.x, b.x, 0) FP8D(a.x, b.x, 1) FP8D(a.x, b.x, 2) FP8D(a.x, b.x, 3)
    FP8D(a.y, b.y, 0) FP8D(a.y, b.y, 1) FP8D(a.y, b.y, 2) FP8D(a.y, b.y, 3)
  }
  const float t = blockSum256(v);
  if (threadIdx.x != 0) return;
  atomicAdd(acc + SLOT(ACC_PERC), t);
  __threadfence();
  unsigned int* cnt = (unsigned int*)(acc + CNT_OFF);
  const unsigned done = atomicAdd(cnt, 1u);
  if (done != 255) return;

  // ---------- final combine (last block only) ----------
  const float NPIX = 2.f * 3.f * 224.f * 224.f;
  const float l1 = acc[SLOT(ACC_L1)] / NPIX;
  const float mse = acc[SLOT(ACC_MSE)] / NPIX;
  const float psnr = 40.f + 10.f * log10f(mse);
  const float cm = 1.f / (3.f * 224.f * 224.f);
  const float color = 0.5f * (fabsf(acc[SLOT(ACC_ST0)] - acc[SLOT(ACC_SP0)]) +
                              fabsf(acc[SLOT(ACC_ST1)] - acc[SLOT(ACC_SP1)])) * cm;
  const float ill = acc[SLOT(ACC_HV)] / 669.f + acc[SLOT(ACC_WV)] / 448.f;
  const float expl = acc[SLOT(ACC_EXP)] / 392.f;
  const float spat = acc[SLOT(ACC_SPAT)] / 6272.f;
  const float perc = acc[SLOT(ACC_PERC)] / 1605632.f;
  const float wms[5] = {0.0448f, 0.2856f, 0.3001f, 0.2363f, 0.1333f};
  const int ns[5] = {214, 102, 46, 18, 4};
  float msum = 0.f;
  for (int img = 0; img < 6; ++img) {
    float prod = 1.f;
    for (int s = 0; s < 5; ++s) {
      const float denom = (float)(ns[s] * ns[s]);
      float vv = (s == 4) ? acc[SSIM_SLOT(s, 0, img)] / denom
                          : acc[SSIM_SLOT(s, 1, img)] / denom;
      vv = fmaxf(vv, 0.f);
      prod *= powf(vv, wms[s]);
    }
    msum += prod;
  }
  const float msssim = msum / 6.f;
  out[0] = l1 + 0.06f * perc + 0.0083f * psnr + 0.25f * color +
           0.5f * (1.f - msssim) + 0.1f * expl + 0.1f * ill + 0.1f * spat;
}

extern "C" void kernel_launch(void* const* d_in, const int* in_sizes, int n_in,
                              void* d_out, int out_size, void* d_ws, size_t ws_size,
                              hipStream_t stream) {
  const float* yt = (const float*)d_in[0];
  const float* yp = (const float*)d_in[1];
  const float* W7[7]; const float* B7[7];
  for (int i = 0; i < 7; ++i) {
    W7[i] = (const float*)d_in[2 + 2 * i];
    B7[i] = (const float*)d_in[3 + 2 * i];
  }

  char* ws = (char*)d_ws;
  float* acc = (float*)ws;
  const float* zpage = acc + ZPAGE_FLOAT_OFF;  // zeroed by memset, never written
  size_t off = 16384;
  auto align256 = [&]() { off = (off + 255) & ~(size_t)255; };
  align256(); unsigned char* C1  = (unsigned char*)(ws + off); off += (size_t)4 * 226 * 226 * 64;
  align256(); unsigned char* Pl1 = (unsigned char*)(ws + off); off += (size_t)4 * 114 * 114 * 64;
  align256(); unsigned char* C3  = (unsigned char*)(ws + off); off += (size_t)4 * 114 * 114 * 128;
  align256(); unsigned char* Pl2 = (unsigned char*)(ws + off); off += (size_t)4 * 58 * 58 * 128;
  align256(); unsigned char* C5  = (unsigned char*)(ws + off); off += (size_t)4 * 58 * 58 * 256;
  align256(); unsigned char* C6  = (unsigned char*)(ws + off); off += (size_t)4 * 58 * 58 * 256;
  align256(); unsigned char* F   = (unsigned char*)(ws + off); off += (size_t)4 * 58 * 58 * 256;
  align256(); unsigned char* WT  = (unsigned char*)(ws + off); off += (size_t)1732608;
  align256(); float* pyrX = (float*)(ws + off); off += (size_t)100000 * 4;
  align256(); float* pyrY = (float*)(ws + off); off += (size_t)100000 * 4;
  if (ws_size < off) return;

  GW gw;
  {
    double vv[11]; double s = 0.0;
    for (int i = 0; i < 11; ++i) { const double c = i - 5.0; vv[i] = exp(-(c * c) / 4.5); s += vv[i]; }
    for (int i = 0; i < 11; ++i) gw.g[i] = (float)(vv[i] / s);
  }

  hipMemsetAsync(acc, 0, 16384, stream);

  const int co[7] = {64, 64, 128, 128, 256, 256, 256};
  const int ci[7] = {3, 64, 64, 128, 128, 256, 256};
  MegaArgs ma;
  size_t wtOff[7];
  {
    int e = 0;
    for (int i = 1; i < 7; ++i) {
      ma.pa.w[i - 1] = W7[i]; ma.pa.co[i - 1] = co[i]; ma.pa.ci[i - 1] = ci[i];
      ma.pa.wcum[i - 1] = e; wtOff[i] = (size_t)e; e += co[i] * 9 * ci[i];
    }
    ma.pa.wcum[6] = e;
    ma.nW4 = e / 4;
    unsigned char* bufs[6] = {C1, Pl1, C3, Pl2, C5, C6};
    const int hh[6] = {224, 112, 112, 56, 56, 56};
    const int cc[6] = {64, 64, 128, 128, 256, 256};
    int z = 0;
    for (int i = 0; i < 6; ++i) {
      ma.pa.zp[i] = bufs[i]; ma.pa.zH[i] = hh[i];
      ma.pa.zcum[i] = z;
      const int perC = (2 * (hh[i] + 2) * 32 + 2 * hh[i] * 32) >> 4;  // 16B chunks/plane
      z += (4 * cc[i] / 32) * perC;
    }
    ma.pa.zcum[6] = z;
    ma.nPrep = (ma.nW4 + z + 255) / 256;
  }
  ma.wdst = WT;
  ma.w0 = W7[0]; ma.b0 = B7[0];
  ma.c1 = C1;
  ma.pyrX = pyrX; ma.pyrY = pyrY;
  ma.acc = acc;
  ma.nBasic = 294;
  ma.nPyr = 196 * 6 * 2;
  ma.nPS = 32;
  const int nConv1 = 28 * 28 * 8;
  const int megaBlocks = ma.nPrep + ma.nBasic + ma.nPyr + ma.nPS + nConv1;

  mega_k<<<megaBlocks, 256, 0, stream>>>(ma, yt, yp);

  // VGG19[:16] conv chain in fp8. conv2 back to plain conv+pool (sheds ssim
  // so L3 starts sooner); ssim tiles ride the deep layers' idle CUs instead.
  conv_mfma<64, false, true>  <<<dim3(4, 224, 2), 256, 0, stream>>>(C1,  WT + wtOff[1], B7[1], Pl1, zpage, 224, 56);
  conv_mfma<64, false, false> <<<dim3(2, 4 * 28, 4), 256, 0, stream>>>(Pl1, WT + wtOff[2], B7[2], C3, zpage, 112, 28);
  conv_mfma<128, false, true> <<<dim3(2, 4 * 28, 4), 256, 0, stream>>>(C3,  WT + wtOff[3], B7[3], Pl2, zpage, 112, 28);
  conv_deep_ssim_k<128><<<dim3(1, 56, 18), 256, 0, stream>>>(
      Pl2, WT + wtOff[4], B7[4], C5, zpage, yt, yp, pyrX, pyrY, acc, gw, 0, 518);
  conv_deep_ssim_k<256><<<dim3(1, 56, 18), 256, 0, stream>>>(
      C5, WT + wtOff[5], B7[5], C6, zpage, yt, yp, pyrX, pyrY, acc, gw, 518, 518);
  conv_deep_ssim_k<256><<<dim3(1, 56, 18), 256, 0, stream>>>(
      C6, WT + wtOff[6], B7[6], F, zpage, yt, yp, pyrX, pyrY, acc, gw, 1036, 518);
  perc_final_k<<<256, 256, 0, stream>>>(F, acc, (float*)d_out);
}

// Round 15
// 251.632 us; speedup vs baseline: 1.0258x; 1.0258x over previous
//
#include <hip/hip_runtime.h>
#include <cmath>

typedef __attribute__((ext_vector_type(8))) short  short8;
typedef __attribute__((ext_vector_type(4))) float  floatx4;
typedef __attribute__((ext_vector_type(8))) unsigned short ushort8;
typedef __attribute__((ext_vector_type(8))) unsigned char uchar8v;

// Accumulator slots spread 64B apart to avoid same-cacheline atomic serialization.
#define SLOT(i) ((i) * 16)
#define ACC_L1   0
#define ACC_MSE  1
#define ACC_ST0  2
#define ACC_ST1  3
#define ACC_SP0  4
#define ACC_SP1  5
#define ACC_HV   6
#define ACC_WV   7
#define ACC_EXP  8
#define ACC_SPAT 9
#define ACC_PERC 10
#define CNT_OFF  240          // perc completion counter (memset'd to 0)
#define SSIM_SLOT(scale, cs, img) (256 + ((scale) * 12 + (cs) * 6 + (img)) * 16)
// zero page for OOB global_load_lds lanes: bytes [12800, 16384) of the
// memset'd acc region — never written by any atomic. Always zero.
#define ZPAGE_FLOAT_OFF 3200

struct GW { float g[11]; };

__device__ __forceinline__ float waveSum(float v) {
#pragma unroll
  for (int o = 32; o > 0; o >>= 1) v += __shfl_down(v, o, 64);
  return v;
}

__device__ __forceinline__ float blockSum256(float v) {
  __shared__ float red[4];
  const int tid = threadIdx.x;
  v = waveSum(v);
  __syncthreads();
  if ((tid & 63) == 0) red[tid >> 6] = v;
  __syncthreads();
  return red[0] + red[1] + red[2] + red[3];
}

// pack 4 floats -> 4 OCP e4m3 bytes (HW cvt, RNE)
__device__ __forceinline__ unsigned int pk_fp8x4(float v0, float v1, float v2, float v3) {
  int p = __builtin_amdgcn_cvt_pk_fp8_f32(v0, v1, 0, false);
  p = __builtin_amdgcn_cvt_pk_fp8_f32(v2, v3, p, true);
  return (unsigned int)p;
}

// async global->LDS, 16B per lane; LDS dest is wave-linear (base + lane*16).
__device__ __forceinline__ void gload16(const unsigned char* g, unsigned char* l) {
  __builtin_amdgcn_global_load_lds(
      (const __attribute__((address_space(1))) void*)g,
      (__attribute__((address_space(3))) void*)l, 16, 0, 0);
}

// shared ssim tile body: computes one (scale, tile, img) contribution.
// sX/sY/sV are caller-provided LDS aliases. bid in [0,259).
__device__ __forceinline__ void ssim_tile(
    int bid, int img, const float* __restrict__ yt, const float* __restrict__ yp,
    const float* __restrict__ pyrX, const float* __restrict__ pyrY,
    float* __restrict__ acc, const GW& gw,
    float (*sX)[27], float (*sY)[27], float (*sV)[16][27]) {
  int s = 0;
  if (bid >= 196) s = 1;
  if (bid >= 245) s = 2;
  if (bid >= 254) s = 3;
  if (bid >= 258) s = 4;
  const int cumA[5]   = {0, 196, 245, 254, 258};
  const int tilesA[5] = {14, 7, 3, 2, 1};
  const int dimsA[5]  = {224, 112, 56, 28, 14};
  const int offsA[5]  = {0, 0, 75264, 94080, 98784};
  const int t = bid - cumA[s];
  const int tiles = tilesA[s];
  const int n = dimsA[s];
  const int m = n - 10;
  const int tid = threadIdx.x;
  const int ty0 = (t / tiles) * 16;
  const int tx0 = (t - (t / tiles) * tiles) * 16;
  const float* Xb = ((s == 0) ? yt : pyrX + offsA[s]) + (size_t)img * n * n;
  const float* Yb = ((s == 0) ? yp : pyrY + offsA[s]) + (size_t)img * n * n;

  for (int e = tid; e < 26 * 26; e += 256) {
    const int r = e / 26, c = e - (e / 26) * 26;
    const int gy = ty0 + r, gx = tx0 + c;
    float xv = 0.f, yv = 0.f;
    if (gy < n && gx < n) {
      xv = Xb[(size_t)gy * n + gx];
      yv = Yb[(size_t)gy * n + gx];
    }
    sX[r][c] = xv; sY[r][c] = yv;
  }
  __syncthreads();

  for (int e = tid; e < 16 * 26; e += 256) {
    const int r = e / 26, c = e - (e / 26) * 26;
    float sx = 0.f, sy = 0.f, sxx = 0.f, syy = 0.f, sxy = 0.f;
#pragma unroll
    for (int tt = 0; tt < 11; ++tt) {
      const float xv = sX[r + tt][c];
      const float yv = sY[r + tt][c];
      const float g = gw.g[tt];
      sx += g * xv; sy += g * yv;
      sxx += g * xv * xv; syy += g * yv * yv; sxy += g * xv * yv;
    }
    sV[0][r][c] = sx; sV[1][r][c] = sy;
    sV[2][r][c] = sxx; sV[3][r][c] = syy; sV[4][r][c] = sxy;
  }
  __syncthreads();

  float sv = 0.f, cv = 0.f;
  {
    const int r = tid >> 4, c = tid & 15;
    if (ty0 + r < m && tx0 + c < m) {
      float mu1 = 0.f, mu2 = 0.f, e11 = 0.f, e22 = 0.f, e12 = 0.f;
#pragma unroll
      for (int tt = 0; tt < 11; ++tt) {
        const float g = gw.g[tt];
        mu1 += g * sV[0][r][c + tt];
        mu2 += g * sV[1][r][c + tt];
        e11 += g * sV[2][r][c + tt];
        e22 += g * sV[3][r][c + tt];
        e12 += g * sV[4][r][c + tt];
      }
      const float C1 = 1e-4f, C2 = 9e-4f;
      const float s11 = e11 - mu1 * mu1;
      const float s22 = e22 - mu2 * mu2;
      const float s12 = e12 - mu1 * mu2;
      cv = (2.f * s12 + C2) / (s11 + s22 + C2);
      sv = ((2.f * mu1 * mu2 + C1) / (mu1 * mu1 + mu2 * mu2 + C1)) * cv;
    }
  }
  float tsum = blockSum256(sv);
  if (tid == 0) atomicAdd(acc + SSIM_SLOT(s, 0, img), tsum);
  tsum = blockSum256(cv);
  if (tid == 0) atomicAdd(acc + SSIM_SLOT(s, 1, img), tsum);
}

// ---------------- mega front-section kernel (R8 structure, unchanged) ------

struct PrepArgs {
  const float* w[6];
  int co[6], ci[6];
  int wcum[7];          // element units
  unsigned char* zp[6];
  int zH[6];
  int zcum[7];          // 16B-chunk units
};

struct MegaArgs {
  PrepArgs pa;
  unsigned char* wdst;
  const float* w0;
  const float* b0;
  unsigned char* c1;
  float* pyrX;
  float* pyrY;
  float* acc;
  int nPrep, nBasic, nPyr, nPS, nW4;
};

__global__ __launch_bounds__(256) void mega_k(MegaArgs A,
                                              const float* __restrict__ yt,
                                              const float* __restrict__ yp) {
  __shared__ float smem[684];
  const int tid = threadIdx.x;
  int bid = blockIdx.x;

  // ---------- prep (vectorized) ----------
  if (bid < A.nPrep) {
    const int idx = bid * 256 + tid;
    const PrepArgs& a = A.pa;
    if (idx < A.nW4) {
      const int e0 = idx * 4;
      int L = 0;
      while (e0 >= a.wcum[L + 1]) ++L;
      const int r = e0 - a.wcum[L];
      const int Cin = a.ci[L];
      const int cin = r % Cin;
      const int t = r / Cin;
      const int tap = t % 9;
      const int cout = t / 9;
      const float* wsrc = a.w[L] + ((size_t)cout * Cin + cin) * 9 + tap;
      *(unsigned int*)(A.wdst + e0) =
          pk_fp8x4(wsrc[0] * 8.f, wsrc[9] * 8.f, wsrc[18] * 8.f, wsrc[27] * 8.f);
      return;
    }
    const int zi = idx - A.nW4;
    if (zi >= a.zcum[6]) return;
    int b = 0;
    while (zi >= a.zcum[b + 1]) ++b;
    const int H = a.zH[b];
    const int rowE = (H + 2) * 32;
    const int perC = (2 * rowE + 2 * H * 32) >> 4;   // 16B chunks per plane
    const int k = zi - a.zcum[b];
    const int pl = k / perC;
    const int k0 = (k - pl * perC) << 4;
    size_t o;
    if (k0 < rowE) o = k0;
    else if (k0 < 2 * rowE) o = (size_t)(H + 1) * rowE + (k0 - rowE);
    else {
      const int kk = k0 - 2 * rowE;
      const int y = kk / 64 + 1;
      const int r = kk & 63;
      o = (size_t)y * rowE + ((r < 32) ? (size_t)r : ((size_t)(H + 1) * 32 + (r - 32)));
    }
    *(uint4*)(a.zp[b] + (size_t)pl * (H + 2) * rowE + o) = (uint4){0, 0, 0, 0};
    return;
  }
  bid -= A.nPrep;

  // ---------- basic_stats ----------
  if (bid < A.nBasic) {
    float* acc = A.acc;
    const int i4 = bid * 256 + tid;  // 0..75263
    const int idx = i4 * 4;
    const float4 t4 = *(const float4*)(yt + idx);
    const float4 p4 = *(const float4*)(yp + idx);
    float l1 = 0.f, mse = 0.f, st0 = 0.f, st1 = 0.f, sp0 = 0.f, sp1 = 0.f, hv = 0.f, wv = 0.f;
#define BTERM(tt, pp) { const float d = (pp) - (tt); const float ad = fabsf(d); \
                        l1 += (ad < 1.f) ? 0.5f * d * d : ad - 0.5f; mse += d * d; }
    BTERM(t4.x, p4.x) BTERM(t4.y, p4.y) BTERM(t4.z, p4.z) BTERM(t4.w, p4.w)
#undef BTERM
    const float ts = t4.x + t4.y + t4.z + t4.w;
    const float ps = p4.x + p4.y + p4.z + p4.w;
    if (i4 < 37632) { st0 = ts; sp0 = ps; } else { st1 = ts; sp1 = ps; }
    const int h = (idx / 224) % 224;
    if (h < 223) {
      const float4 pn = *(const float4*)(yp + idx + 224);
      float d;
      d = pn.x - p4.x; hv += d * d;
      d = pn.y - p4.y; hv += d * d;
      d = pn.z - p4.z; hv += d * d;
      d = pn.w - p4.w; hv += d * d;
    }
    {
      const int w = idx % 224;
      float d;
      d = p4.y - p4.x; wv += d * d;
      d = p4.z - p4.y; wv += d * d;
      d = p4.w - p4.z; wv += d * d;
      if (w < 220) { d = yp[idx + 4] - p4.w; wv += d * d; }
    }
    float s;
    s = blockSum256(l1);  if (tid == 0) atomicAdd(acc + SLOT(ACC_L1), s);
    s = blockSum256(mse); if (tid == 0) atomicAdd(acc + SLOT(ACC_MSE), s);
    s = blockSum256(st0); if (tid == 0) atomicAdd(acc + SLOT(ACC_ST0), s);
    s = blockSum256(st1); if (tid == 0) atomicAdd(acc + SLOT(ACC_ST1), s);
    s = blockSum256(sp0); if (tid == 0) atomicAdd(acc + SLOT(ACC_SP0), s);
    s = blockSum256(sp1); if (tid == 0) atomicAdd(acc + SLOT(ACC_SP1), s);
    s = blockSum256(hv);  if (tid == 0) atomicAdd(acc + SLOT(ACC_HV), s);
    s = blockSum256(wv);  if (tid == 0) atomicAdd(acc + SLOT(ACC_WV), s);
    return;
  }
  bid -= A.nBasic;

  // ---------- pyramid ----------
  if (bid < A.nPyr) {
    float (*sA)[17] = (float(*)[17])smem;          // 272
    float (*s1)[9]  = (float(*)[9])(smem + 272);   // 72
    float (*s2)[5]  = (float(*)[5])(smem + 344);   // 20
    float (*s3)[3]  = (float(*)[3])(smem + 364);   // 6
    const int tile = bid % 196;
    const int img = (bid / 196) % 6;
    const int zt = bid / (196 * 6);
    const int ty = tile / 14, tx = tile - ty * 14;
    const float* src = (zt ? yp : yt) + (size_t)img * 224 * 224;
    float* dst = zt ? A.pyrY : A.pyrX;
    const int r = tid >> 4, c = tid & 15;
    sA[r][c] = src[(size_t)(ty * 16 + r) * 224 + tx * 16 + c];
    __syncthreads();
    if (tid < 64) {
      const int r1 = tid >> 3, c1 = tid & 7;
      const float m = 0.25f * (sA[2 * r1][2 * c1] + sA[2 * r1][2 * c1 + 1] +
                               sA[2 * r1 + 1][2 * c1] + sA[2 * r1 + 1][2 * c1 + 1]);
      dst[(size_t)img * 12544 + (ty * 8 + r1) * 112 + tx * 8 + c1] = m;
      s1[r1][c1] = m;
    }
    __syncthreads();
    if (tid < 16) {
      const int r2 = tid >> 2, c2 = tid & 3;
      const float m = 0.25f * (s1[2 * r2][2 * c2] + s1[2 * r2][2 * c2 + 1] +
                               s1[2 * r2 + 1][2 * c2] + s1[2 * r2 + 1][2 * c2 + 1]);
      dst[75264 + (size_t)img * 3136 + (ty * 4 + r2) * 56 + tx * 4 + c2] = m;
      s2[r2][c2] = m;
    }
    __syncthreads();
    if (tid < 4) {
      const int r3 = tid >> 1, c3 = tid & 1;
      const float m = 0.25f * (s2[2 * r3][2 * c3] + s2[2 * r3][2 * c3 + 1] +
                               s2[2 * r3 + 1][2 * c3] + s2[2 * r3 + 1][2 * c3 + 1]);
      dst[94080 + (size_t)img * 784 + (ty * 2 + r3) * 28 + tx * 2 + c3] = m;
      s3[r3][c3] = m;
    }
    __syncthreads();
    if (tid == 0) {
      const float m = 0.25f * (s3[0][0] + s3[0][1] + s3[1][0] + s3[1][1]);
      dst[98784 + (size_t)img * 196 + ty * 14 + tx] = m;
    }
    return;
  }
  bid -= A.nPyr;

  // ---------- pooled-lum tile + spat + exposure ----------
  if (bid < A.nPS) {
    float* acc = A.acc;
    float (*sOp)[19] = (float(*)[19])smem;          // 18x19
    float (*sEp)[19] = (float(*)[19])(smem + 342);  // 18x19
    const int b = bid >> 4;                 // img
    const int tq = bid & 15;
    const int ty0 = (tq >> 2) * 16, tx0 = (tq & 3) * 16;
    for (int e = tid; e < 18 * 18; e += 256) {
      const int r = e / 18, c = e - (e / 18) * 18;
      const int gy = ty0 - 1 + r, gx = tx0 - 1 + c;
      float vo = 0.f, ve = 0.f;
      if (gy >= 0 && gy < 56 && gx >= 0 && gx < 56) {
        float so = 0.f, se = 0.f;
        for (int ch = 0; ch < 3; ++ch)
#pragma unroll
          for (int dy = 0; dy < 4; ++dy) {
            const size_t off = (((size_t)b * 3 + ch) * 224 + (gy * 4 + dy)) * 224 + gx * 4;
            const float4 a = *(const float4*)(yt + off);
            const float4 ee = *(const float4*)(yp + off);
            so += a.x + a.y + a.z + a.w;
            se += ee.x + ee.y + ee.z + ee.w;
          }
        vo = so * (1.f / 48.f);
        ve = se * (1.f / 48.f);
      }
      sOp[r][c] = vo; sEp[r][c] = ve;
    }
    __syncthreads();
    float v = 0.f;
    {
      const int r = tid >> 4, c = tid & 15;
      const int gy = ty0 + r, gx = tx0 + c;
      if (gy < 56 && gx < 56) {
        const float oc = sOp[r + 1][c + 1], ec = sEp[r + 1][c + 1];
        const float ol = sOp[r + 1][c],     el = sEp[r + 1][c];
        const float orr = sOp[r + 1][c + 2], er = sEp[r + 1][c + 2];
        const float ou = sOp[r][c + 1],     eu = sEp[r][c + 1];
        const float od = sOp[r + 2][c + 1], ed = sEp[r + 2][c + 1];
        float d;
        d = (oc - ol) - (ec - el);   v += d * d;
        d = (oc - orr) - (ec - er);  v += d * d;
        d = (oc - ou) - (ec - eu);   v += d * d;
        d = (oc - od) - (ec - ed);   v += d * d;
      }
    }
    const float t = blockSum256(v);
    if (tid == 0) atomicAdd(acc + SLOT(ACC_SPAT), t);
    if (tid < 16) {
      const int ey = tid >> 2, ex = tid & 3;
      if (ty0 + 4 * ey < 56 && tx0 + 4 * ex < 56) {
        float ssum = 0.f;
#pragma unroll
        for (int dy = 0; dy < 4; ++dy)
#pragma unroll
          for (int dx = 0; dx < 4; ++dx)
            ssum += sEp[4 * ey + dy + 1][4 * ex + dx + 1];
        const float m = ssum * (1.f / 16.f) - 0.6f;
        atomicAdd(acc + SLOT(ACC_EXP), m * m);
      }
    }
    return;
  }
  bid -= A.nPS;

  // ---------- conv1 ----------
  {
    float (*sIn)[10][12] = (float(*)[10][12])smem;
    const int zf = bid / 784;
    const int rem = bid - zf * 784;
    const int by = rem / 28, bx = rem - by * 28;
    const int tx = tid & 7, ty = (tid >> 3) & 7, tz = tid >> 6;
    const int img = zf >> 1;
    const int zb = zf & 1;
    const float* in = ((img >> 1) ? yp : yt) + (size_t)(img & 1) * 3 * 224 * 224;
    const int x0 = bx << 3, y0 = by << 3;
    const int x = x0 + tx, y = y0 + ty;
    int wrow = (zb * 32 + tz * 8) * 27;
    wrow = __builtin_amdgcn_readfirstlane(wrow);

    for (int el = tid; el < 300; el += 256) {
      const int ci = el / 100;
      const int r2 = el - ci * 100;
      const int r = r2 / 10, cl = r2 - r * 10;
      const int gy = y0 - 1 + r, gx = x0 - 1 + cl;
      float v = 0.f;
      if (gy >= 0 && gy < 224 && gx >= 0 && gx < 224)
        v = in[((size_t)ci * 224 + gy) * 224 + gx];
      sIn[ci][r][cl] = v;
    }
    __syncthreads();

    float a[8];
#pragma unroll
    for (int j = 0; j < 8; ++j) a[j] = 0.f;
#pragma unroll
    for (int ci = 0; ci < 3; ++ci) {
      float xv[9];
#pragma unroll
      for (int ky = 0; ky < 3; ++ky)
#pragma unroll
        for (int kx = 0; kx < 3; ++kx)
          xv[ky * 3 + kx] = sIn[ci][ty + ky][tx + kx];
      const float* wp = A.w0 + wrow + ci * 9;
#pragma unroll
      for (int j = 0; j < 8; ++j)
#pragma unroll
        for (int k = 0; k < 9; ++k)
          a[j] = fmaf(xv[k], wp[27 * j + k], a[j]);
    }
    const int coB = zb * 32 + tz * 8;
    float r[8];
#pragma unroll
    for (int j = 0; j < 8; ++j) r[j] = fmaxf(a[j] + A.b0[coB + j], 0.f);
    const size_t o = (((size_t)(zb * 4 + img) * 226 + (y + 1)) * 226 + (x + 1)) * 32 + tz * 8;
    uint2 rv;
    rv.x = pk_fp8x4(r[0], r[1], r[2], r[3]);
    rv.y = pk_fp8x4(r[4], r[5], r[6], r[7]);
    *(uint2*)(A.c1 + o) = rv;
  }
}

// ---------------- VGG conv (fp8 e4m3, channel-block-major) ----------------
// Activation layout: buf[zb][img][H+2][W+2][32]. Staging = global_load_lds
// width=16 (R9, m151). DB=false: single-buffer 2-barrier, 4 blocks/CU.
// DB=true (W=56 deep layers): 2-phase double-buffer (R10, neutral; kept).
// POOL=true (R13): fused 2x2 maxpool epilogue (windows align inside the
// block tile; byte-exact vs the old pool_nhwc; kills the T0 round-trip).
template<int CIN, bool DB, bool POOL>
__global__ __launch_bounds__(256, (DB ? 2 : 4)) void conv_mfma(
    const unsigned char* __restrict__ in, const unsigned char* __restrict__ wtp,
    const float* __restrict__ bias, unsigned char* __restrict__ out,
    const float* __restrict__ zpage, int W, int rowsPI) {
  constexpr int NSLAB = CIN / 32;
  constexpr int NBUF = DB ? 2 : 1;
  constexpr int ASTB = 304;
  constexpr int BSTB = 48;
  constexpr int NBRUN = 6 * 66;
  constexpr int NPX = 66;
  constexpr int ASLOT = 32 * 19;
  constexpr int BSLOT = NBRUN * 3;
  constexpr int NAI = 3;
  constexpr int NBI = 5;
  __shared__ __align__(16) unsigned char As[NBUF][32 * ASTB];
  __shared__ __align__(16) unsigned char Bs[NBUF][NBRUN * BSTB];

  const int tid = threadIdx.x;
  const int lane = tid & 63;
  const int wave = tid >> 6;
  const int quad = lane >> 4;
  const int lr = lane & 15;
  const int img = blockIdx.y / rowsPI;
  const int y0 = (blockIdx.y - img * rowsPI) * 4;
  const int x0 = blockIdx.x * 64;
  const int cob = blockIdx.z * 32;
  const int Wp = W + 2;
  const int H = rowsPI * 4;
  const size_t IPL = (size_t)(H + 2) * Wp * 32;
  const unsigned char* inI = in + (size_t)img * IPL;
  const int Wo = W >> 1, Ho = H >> 1;
  const size_t OPL = POOL ? (size_t)(Ho + 2) * (Wo + 2) * 32 : IPL;
  unsigned char* outI = out + ((size_t)blockIdx.z * 4 + img) * OPL;

  floatx4 acc[2][4];
#pragma unroll
  for (int m = 0; m < 2; ++m)
#pragma unroll
    for (int n = 0; n < 4; ++n) acc[m][n] = (floatx4){0.f, 0.f, 0.f, 0.f};

  const int abase = lr * ASTB + quad * 8;

  const unsigned char* aptr[NAI];
  bool aok[NAI];
#pragma unroll
  for (int i = 0; i < NAI; ++i) {
    const int sl = tid + i * 256;
    aok[i] = sl < ASLOT;
    const int cout = aok[i] ? (sl / 19) : 0;
    const int r = sl - cout * 19;
    const int rr = (r >= 18) ? 17 : r;
    const int tap = rr >> 1, part = rr & 1;
    aptr[i] = wtp + ((size_t)(cob + cout) * 9 + tap) * CIN + part * 16;
  }
  const unsigned char* bptr[NBI];
  unsigned int bstep[NBI];
  bool bok[NBI];
#pragma unroll
  for (int i = 0; i < NBI; ++i) {
    const int sl = tid + i * 256;
    bok[i] = sl < BSLOT;
    const int run = sl / 3;
    const int r = sl - run * 3;
    const int part = (r >= 2) ? 1 : r;
    const int row = run / NPX;
    const int px = run - row * NPX;
    const int gx = x0 + px;
    if (bok[i] && gx < Wp) {
      bptr[i] = inI + ((size_t)(y0 + row) * Wp + gx) * 32 + part * 16;
      bstep[i] = (unsigned int)(4 * IPL);
    } else {
      bptr[i] = (const unsigned char*)zpage;
      bstep[i] = 0;
    }
  }

  auto stage = [&](int buf) {
#pragma unroll
    for (int i = 0; i < NAI; ++i)
      if (aok[i]) {
        gload16(aptr[i], As[buf] + (tid + i * 256) * 16);
        aptr[i] += 32;
      }
#pragma unroll
    for (int i = 0; i < NBI; ++i)
      if (bok[i]) {
        gload16(bptr[i], Bs[buf] + (tid + i * 256) * 16);
        bptr[i] += bstep[i];
      }
  };

  auto mfma_slab = [&](int buf) {
#pragma unroll
    for (int dy = 0; dy < 3; ++dy)
#pragma unroll
      for (int dx = 0; dx < 3; ++dx) {
        const int tap = dy * 3 + dx;
        const long af0 = *(const long*)(As[buf] + abase + tap * 32);
        const long af1 = *(const long*)(As[buf] + abase + 16 * ASTB + tap * 32);
        long bfr[4];
#pragma unroll
        for (int n = 0; n < 4; ++n)
          bfr[n] = *(const long*)(Bs[buf] + ((wave + dy) * NPX + n * 16 + lr + dx) * BSTB + quad * 8);
#pragma unroll
        for (int n = 0; n < 4; ++n) {
          acc[0][n] = __builtin_amdgcn_mfma_f32_16x16x32_fp8_fp8(af0, bfr[n], acc[0][n], 0, 0, 0);
          acc[1][n] = __builtin_amdgcn_mfma_f32_16x16x32_fp8_fp8(af1, bfr[n], acc[1][n], 0, 0, 0);
        }
      }
  };

  if constexpr (!DB) {
    for (int s = 0; s < NSLAB; ++s) {
      __syncthreads();
      stage(0);
      __syncthreads();
      mfma_slab(0);
    }
  } else {
    stage(0);
    __syncthreads();
    for (int s = 0; s < NSLAB; ++s) {
      const int cur = s & 1;
      if (s + 1 < NSLAB) stage(cur ^ 1);
      mfma_slab(cur);
      __syncthreads();
    }
  }

  if constexpr (!POOL) {
#pragma unroll
    for (int m = 0; m < 2; ++m) {
      const int cb = cob + m * 16 + quad * 4;
#pragma unroll
      for (int n = 0; n < 4; ++n) {
        const int px = x0 + n * 16 + lr;
        if (px < W) {
          const float v0 = fmaxf(acc[m][n].x * 0.125f + bias[cb + 0], 0.f);
          const float v1 = fmaxf(acc[m][n].y * 0.125f + bias[cb + 1], 0.f);
          const float v2 = fmaxf(acc[m][n].z * 0.125f + bias[cb + 2], 0.f);
          const float v3 = fmaxf(acc[m][n].w * 0.125f + bias[cb + 3], 0.f);
          *(unsigned int*)(outI + ((size_t)(y0 + wave + 1) * Wp + px + 1) * 32 +
                           m * 16 + quad * 4) = pk_fp8x4(v0, v1, v2, v3);
        }
      }
    }
  } else {
    // fused 2x2 maxpool epilogue via LDS tile sT[4 rows][64 px][32 ch]
    __syncthreads();   // all waves done reading Bs
    unsigned char* sT = Bs[0];
#pragma unroll
    for (int m = 0; m < 2; ++m) {
      const int cb = cob + m * 16 + quad * 4;
#pragma unroll
      for (int n = 0; n < 4; ++n) {
        const int px = n * 16 + lr;
        const float v0 = fmaxf(acc[m][n].x * 0.125f + bias[cb + 0], 0.f);
        const float v1 = fmaxf(acc[m][n].y * 0.125f + bias[cb + 1], 0.f);
        const float v2 = fmaxf(acc[m][n].z * 0.125f + bias[cb + 2], 0.f);
        const float v3 = fmaxf(acc[m][n].w * 0.125f + bias[cb + 3], 0.f);
        *(unsigned int*)(sT + ((wave * 64 + px) * 32 + m * 16 + quad * 4)) =
            pk_fp8x4(v0, v1, v2, v3);
      }
    }
    __syncthreads();
    const int ch8 = (tid & 3) * 8;
    const int co = (tid >> 2) & 31;
    const int ro = tid >> 7;
    const int pxo = (x0 >> 1) + co;
    if (pxo < Wo) {
      const uchar8v a = *(const uchar8v*)(sT + ((2 * ro) * 64 + 2 * co) * 32 + ch8);
      const uchar8v b = *(const uchar8v*)(sT + ((2 * ro) * 64 + 2 * co + 1) * 32 + ch8);
      const uchar8v c = *(const uchar8v*)(sT + ((2 * ro + 1) * 64 + 2 * co) * 32 + ch8);
      const uchar8v d = *(const uchar8v*)(sT + ((2 * ro + 1) * 64 + 2 * co + 1) * 32 + ch8);
      const uchar8v r = __builtin_elementwise_max(__builtin_elementwise_max(a, b),
                                                  __builtin_elementwise_max(c, d));
      *(uchar8v*)(outI + ((size_t)((y0 >> 1) + ro + 1) * (Wo + 2) + (pxo + 1)) * 32 + ch8) = r;
    }
  }
}

// ---------------- fused: conv layer-2 (CIN=64, W=224) + pool + MS-SSIM ------
// R11/R12 fusion (ssim tiles ride conv L2's latency bubbles at 28.7KB LDS /
// 4 blocks/CU — R14's deep-layer move regressed: 57.5KB LDS slots halved
// ssim residency) + R13 pooled epilogue (writes Pl1 directly).
__global__ __launch_bounds__(256, 4) void conv2_ssim_k(
    const unsigned char* __restrict__ in, const unsigned char* __restrict__ wtp,
    const float* __restrict__ bias, unsigned char* __restrict__ out,
    const float* __restrict__ zpage,
    const float* __restrict__ yt, const float* __restrict__ yp,
    const float* __restrict__ pyrX, const float* __restrict__ pyrY,
    float* __restrict__ acc_g, GW gw) {
  constexpr int CIN = 64;
  constexpr int NSLAB = CIN / 32;
  constexpr int ASTB = 304;
  constexpr int BSTB = 48;
  constexpr int NBRUN = 6 * 66;
  constexpr int NPX = 66;
  constexpr int ASLOT = 32 * 19;
  constexpr int BSLOT = NBRUN * 3;
  constexpr int NAI = 3;
  constexpr int NBI = 5;
  const int W = 224, rowsPI = 56;
  __shared__ __align__(16) unsigned char As[32 * ASTB];
  __shared__ __align__(16) unsigned char Bs[NBRUN * BSTB];

  const int tid = threadIdx.x;

  if (blockIdx.z >= 2) {
    // ---------- ssim tiles (block-uniform branch) ----------
    const int sid = (blockIdx.z - 2) * 896 + blockIdx.y * 4 + blockIdx.x;
    if (sid >= 1554) return;
    const int img = sid / 259;
    const int bid = sid - img * 259;
    float (*sX)[27] = (float(*)[27])As;                 // 2808B
    float (*sY)[27] = (float(*)[27])(As + 2816);        // 2808B (<=9728)
    float (*sV)[16][27] = (float(*)[16][27])Bs;         // 8640B (<=19008)
    ssim_tile(bid, img, yt, yp, pyrX, pyrY, acc_g, gw, sX, sY, sV);
    return;
  }

  // ---------- conv with pooled epilogue ----------
  const int lane = tid & 63;
  const int wave = tid >> 6;
  const int quad = lane >> 4;
  const int lr = lane & 15;
  const int img = blockIdx.y / rowsPI;
  const int y0 = (blockIdx.y - img * rowsPI) * 4;
  const int x0 = blockIdx.x * 64;
  const int cob = blockIdx.z * 32;
  const int Wp = W + 2;
  const int H = rowsPI * 4;
  const size_t IPL = (size_t)(H + 2) * Wp * 32;
  const int Wo = W >> 1, Ho = H >> 1;
  const size_t OPL = (size_t)(Ho + 2) * (Wo + 2) * 32;
  const unsigned char* inI = in + (size_t)img * IPL;
  unsigned char* outI = out + ((size_t)blockIdx.z * 4 + img) * OPL;

  floatx4 acc[2][4];
#pragma unroll
  for (int m = 0; m < 2; ++m)
#pragma unroll
    for (int n = 0; n < 4; ++n) acc[m][n] = (floatx4){0.f, 0.f, 0.f, 0.f};

  const int abase = lr * ASTB + quad * 8;

  const unsigned char* aptr[NAI];
  bool aok[NAI];
#pragma unroll
  for (int i = 0; i < NAI; ++i) {
    const int sl = tid + i * 256;
    aok[i] = sl < ASLOT;
    const int cout = aok[i] ? (sl / 19) : 0;
    const int r = sl - cout * 19;
    const int rr = (r >= 18) ? 17 : r;
    const int tap = rr >> 1, part = rr & 1;
    aptr[i] = wtp + ((size_t)(cob + cout) * 9 + tap) * CIN + part * 16;
  }
  const unsigned char* bptr[NBI];
  unsigned int bstep[NBI];
  bool bok[NBI];
#pragma unroll
  for (int i = 0; i < NBI; ++i) {
    const int sl = tid + i * 256;
    bok[i] = sl < BSLOT;
    const int run = sl / 3;
    const int r = sl - run * 3;
    const int part = (r >= 2) ? 1 : r;
    const int row = run / NPX;
    const int px = run - row * NPX;
    const int gx = x0 + px;
    if (bok[i] && gx < Wp) {
      bptr[i] = inI + ((size_t)(y0 + row) * Wp + gx) * 32 + part * 16;
      bstep[i] = (unsigned int)(4 * IPL);
    } else {
      bptr[i] = (const unsigned char*)zpage;
      bstep[i] = 0;
    }
  }

  for (int s = 0; s < NSLAB; ++s) {
    __syncthreads();
#pragma unroll
    for (int i = 0; i < NAI; ++i)
      if (aok[i]) {
        gload16(aptr[i], As + (tid + i * 256) * 16);
        aptr[i] += 32;
      }
#pragma unroll
    for (int i = 0; i < NBI; ++i)
      if (bok[i]) {
        gload16(bptr[i], Bs + (tid + i * 256) * 16);
        bptr[i] += bstep[i];
      }
    __syncthreads();

#pragma unroll
    for (int dy = 0; dy < 3; ++dy)
#pragma unroll
      for (int dx = 0; dx < 3; ++dx) {
        const int tap = dy * 3 + dx;
        const long af0 = *(const long*)(As + abase + tap * 32);
        const long af1 = *(const long*)(As + abase + 16 * ASTB + tap * 32);
        long bfr[4];
#pragma unroll
        for (int n = 0; n < 4; ++n)
          bfr[n] = *(const long*)(Bs + ((wave + dy) * NPX + n * 16 + lr + dx) * BSTB + quad * 8);
#pragma unroll
        for (int n = 0; n < 4; ++n) {
          acc[0][n] = __builtin_amdgcn_mfma_f32_16x16x32_fp8_fp8(af0, bfr[n], acc[0][n], 0, 0, 0);
          acc[1][n] = __builtin_amdgcn_mfma_f32_16x16x32_fp8_fp8(af1, bfr[n], acc[1][n], 0, 0, 0);
        }
      }
  }

  // pooled epilogue (R13): stage fp8 tile in Bs, 2x2 byte-max, write Pl1
  __syncthreads();
  unsigned char* sT = Bs;
#pragma unroll
  for (int m = 0; m < 2; ++m) {
    const int cb = cob + m * 16 + quad * 4;
#pragma unroll
    for (int n = 0; n < 4; ++n) {
      const int px = n * 16 + lr;
      const float v0 = fmaxf(acc[m][n].x * 0.125f + bias[cb + 0], 0.f);
      const float v1 = fmaxf(acc[m][n].y * 0.125f + bias[cb + 1], 0.f);
      const float v2 = fmaxf(acc[m][n].z * 0.125f + bias[cb + 2], 0.f);
      const float v3 = fmaxf(acc[m][n].w * 0.125f + bias[cb + 3], 0.f);
      *(unsigned int*)(sT + ((wave * 64 + px) * 32 + m * 16 + quad * 4)) =
          pk_fp8x4(v0, v1, v2, v3);
    }
  }
  __syncthreads();
  const int ch8 = (tid & 3) * 8;
  const int co = (tid >> 2) & 31;
  const int ro = tid >> 7;
  const int pxo = (x0 >> 1) + co;
  if (pxo < Wo) {
    const uchar8v a = *(const uchar8v*)(sT + ((2 * ro) * 64 + 2 * co) * 32 + ch8);
    const uchar8v b = *(const uchar8v*)(sT + ((2 * ro) * 64 + 2 * co + 1) * 32 + ch8);
    const uchar8v c = *(const uchar8v*)(sT + ((2 * ro + 1) * 64 + 2 * co) * 32 + ch8);
    const uchar8v d = *(const uchar8v*)(sT + ((2 * ro + 1) * 64 + 2 * co + 1) * 32 + ch8);
    const uchar8v r = __builtin_elementwise_max(__builtin_elementwise_max(a, b),
                                                __builtin_elementwise_max(c, d));
    *(uchar8v*)(outI + ((size_t)((y0 >> 1) + ro + 1) * (Wo + 2) + (pxo + 1)) * 32 + ch8) = r;
  }
}

// perceptual + final combine (R15: last-block pattern via atomic counter).
// Stream order guarantees all earlier kernels' atomics are visible when this
// kernel starts; per-block __threadfence before the counter add orders the
// PERC contributions. Counter at acc[CNT_OFF], zeroed by the memset.
#define FP8D(av, bv, J) { const float dd = __builtin_amdgcn_cvt_f32_fp8((av), (J)) - \
                                           __builtin_amdgcn_cvt_f32_fp8((bv), (J)); \
                          v = fmaf(dd, dd, v); }
__global__ __launch_bounds__(256) void perc_final_k(const unsigned char* __restrict__ f,
                                                    float* __restrict__ acc,
                                                    float* __restrict__ out) {
  const int PER = 56 * 56 * 256 / 8;
  const size_t PL = (size_t)58 * 58 * 32;
  float v = 0.f;
  for (int ch = blockIdx.x * 256 + threadIdx.x; ch < 2 * PER; ch += 256 * 256) {
    const int q = ch / PER;
    const int r = ch - q * PER;
    const int e = r * 8;
    const int c = e & 255;
    const int p = e >> 8;
    const int x = p % 56, y = p / 56;
    const int zb = c >> 5;
    const int cw = c & 31;
    const size_t o = (size_t)(zb * 4 + q) * PL + ((size_t)(y + 1) * 58 + (x + 1)) * 32 + cw;
    const uint2 a = *(const uint2*)(f + o);
    const uint2 b = *(const uint2*)(f + o + 2 * PL);
    FP8D(a.x, b.x, 0) FP8D(a.x, b.x, 1) FP8D(a.x, b.x, 2) FP8D(a.x, b.x, 3)
    FP8D(a.y, b.y, 0) FP8D(a.y, b.y, 1) FP8D(a.y, b.y, 2) FP8D(a.y, b.y, 3)
  }
  const float t = blockSum256(v);
  if (threadIdx.x != 0) return;
  atomicAdd(acc + SLOT(ACC_PERC), t);
  __threadfence();
  unsigned int* cnt = (unsigned int*)(acc + CNT_OFF);
  const unsigned done = atomicAdd(cnt, 1u);
  if (done != 255) return;

  // ---------- final combine (last block only) ----------
  const float NPIX = 2.f * 3.f * 224.f * 224.f;
  const float l1 = acc[SLOT(ACC_L1)] / NPIX;
  const float mse = acc[SLOT(ACC_MSE)] / NPIX;
  const float psnr = 40.f + 10.f * log10f(mse);
  const float cm = 1.f / (3.f * 224.f * 224.f);
  const float color = 0.5f * (fabsf(acc[SLOT(ACC_ST0)] - acc[SLOT(ACC_SP0)]) +
                              fabsf(acc[SLOT(ACC_ST1)] - acc[SLOT(ACC_SP1)])) * cm;
  const float ill = acc[SLOT(ACC_HV)] / 669.f + acc[SLOT(ACC_WV)] / 448.f;
  const float expl = acc[SLOT(ACC_EXP)] / 392.f;
  const float spat = acc[SLOT(ACC_SPAT)] / 6272.f;
  const float perc = acc[SLOT(ACC_PERC)] / 1605632.f;
  const float wms[5] = {0.0448f, 0.2856f, 0.3001f, 0.2363f, 0.1333f};
  const int ns[5] = {214, 102, 46, 18, 4};
  float msum = 0.f;
  for (int img = 0; img < 6; ++img) {
    float prod = 1.f;
    for (int s = 0; s < 5; ++s) {
      const float denom = (float)(ns[s] * ns[s]);
      float vv = (s == 4) ? acc[SSIM_SLOT(s, 0, img)] / denom
                          : acc[SSIM_SLOT(s, 1, img)] / denom;
      vv = fmaxf(vv, 0.f);
      prod *= powf(vv, wms[s]);
    }
    msum += prod;
  }
  const float msssim = msum / 6.f;
  out[0] = l1 + 0.06f * perc + 0.0083f * psnr + 0.25f * color +
           0.5f * (1.f - msssim) + 0.1f * expl + 0.1f * ill + 0.1f * spat;
}

extern "C" void kernel_launch(void* const* d_in, const int* in_sizes, int n_in,
                              void* d_out, int out_size, void* d_ws, size_t ws_size,
                              hipStream_t stream) {
  const float* yt = (const float*)d_in[0];
  const float* yp = (const float*)d_in[1];
  const float* W7[7]; const float* B7[7];
  for (int i = 0; i < 7; ++i) {
    W7[i] = (const float*)d_in[2 + 2 * i];
    B7[i] = (const float*)d_in[3 + 2 * i];
  }

  char* ws = (char*)d_ws;
  float* acc = (float*)ws;
  const float* zpage = acc + ZPAGE_FLOAT_OFF;  // zeroed by memset, never written
  size_t off = 16384;
  auto align256 = [&]() { off = (off + 255) & ~(size_t)255; };
  align256(); unsigned char* C1  = (unsigned char*)(ws + off); off += (size_t)4 * 226 * 226 * 64;
  align256(); unsigned char* Pl1 = (unsigned char*)(ws + off); off += (size_t)4 * 114 * 114 * 64;
  align256(); unsigned char* C3  = (unsigned char*)(ws + off); off += (size_t)4 * 114 * 114 * 128;
  align256(); unsigned char* Pl2 = (unsigned char*)(ws + off); off += (size_t)4 * 58 * 58 * 128;
  align256(); unsigned char* C5  = (unsigned char*)(ws + off); off += (size_t)4 * 58 * 58 * 256;
  align256(); unsigned char* C6  = (unsigned char*)(ws + off); off += (size_t)4 * 58 * 58 * 256;
  align256(); unsigned char* F   = (unsigned char*)(ws + off); off += (size_t)4 * 58 * 58 * 256;
  align256(); unsigned char* WT  = (unsigned char*)(ws + off); off += (size_t)1732608;
  align256(); float* pyrX = (float*)(ws + off); off += (size_t)100000 * 4;
  align256(); float* pyrY = (float*)(ws + off); off += (size_t)100000 * 4;
  if (ws_size < off) return;

  GW gw;
  {
    double vv[11]; double s = 0.0;
    for (int i = 0; i < 11; ++i) { const double c = i - 5.0; vv[i] = exp(-(c * c) / 4.5); s += vv[i]; }
    for (int i = 0; i < 11; ++i) gw.g[i] = (float)(vv[i] / s);
  }

  hipMemsetAsync(acc, 0, 16384, stream);

  const int co[7] = {64, 64, 128, 128, 256, 256, 256};
  const int ci[7] = {3, 64, 64, 128, 128, 256, 256};
  MegaArgs ma;
  size_t wtOff[7];
  {
    int e = 0;
    for (int i = 1; i < 7; ++i) {
      ma.pa.w[i - 1] = W7[i]; ma.pa.co[i - 1] = co[i]; ma.pa.ci[i - 1] = ci[i];
      ma.pa.wcum[i - 1] = e; wtOff[i] = (size_t)e; e += co[i] * 9 * ci[i];
    }
    ma.pa.wcum[6] = e;
    ma.nW4 = e / 4;
    unsigned char* bufs[6] = {C1, Pl1, C3, Pl2, C5, C6};
    const int hh[6] = {224, 112, 112, 56, 56, 56};
    const int cc[6] = {64, 64, 128, 128, 256, 256};
    int z = 0;
    for (int i = 0; i < 6; ++i) {
      ma.pa.zp[i] = bufs[i]; ma.pa.zH[i] = hh[i];
      ma.pa.zcum[i] = z;
      const int perC = (2 * (hh[i] + 2) * 32 + 2 * hh[i] * 32) >> 4;  // 16B chunks/plane
      z += (4 * cc[i] / 32) * perC;
    }
    ma.pa.zcum[6] = z;
    ma.nPrep = (ma.nW4 + z + 255) / 256;
  }
  ma.wdst = WT;
  ma.w0 = W7[0]; ma.b0 = B7[0];
  ma.c1 = C1;
  ma.pyrX = pyrX; ma.pyrY = pyrY;
  ma.acc = acc;
  ma.nBasic = 294;
  ma.nPyr = 196 * 6 * 2;
  ma.nPS = 32;
  const int nConv1 = 28 * 28 * 8;
  const int megaBlocks = ma.nPrep + ma.nBasic + ma.nPyr + ma.nPS + nConv1;

  mega_k<<<megaBlocks, 256, 0, stream>>>(ma, yt, yp);

  // VGG19[:16] conv chain in fp8; L2 carries ssim tiles + pooled epilogue
  // (R13 structure — best measured; R14's ssim->deep-layer move reverted).
  conv2_ssim_k<<<dim3(4, 224, 4), 256, 0, stream>>>(
      C1, WT + wtOff[1], B7[1], Pl1, zpage, yt, yp, pyrX, pyrY, acc, gw);
  conv_mfma<64, false, false> <<<dim3(2, 4 * 28, 4), 256, 0, stream>>>(Pl1, WT + wtOff[2], B7[2], C3, zpage, 112, 28);
  conv_mfma<128, false, true> <<<dim3(2, 4 * 28, 4), 256, 0, stream>>>(C3,  WT + wtOff[3], B7[3], Pl2, zpage, 112, 28);
  conv_mfma<128, true, false> <<<dim3(1, 4 * 14, 8), 256, 0, stream>>>(Pl2, WT + wtOff[4], B7[4], C5, zpage, 56, 14);
  conv_mfma<256, true, false> <<<dim3(1, 4 * 14, 8), 256, 0, stream>>>(C5,  WT + wtOff[5], B7[5], C6, zpage, 56, 14);
  conv_mfma<256, true, false> <<<dim3(1, 4 * 14, 8), 256, 0, stream>>>(C6,  WT + wtOff[6], B7[6], F,  zpage, 56, 14);
  perc_final_k<<<256, 256, 0, stream>>>(F, acc, (float*)d_out);
}